// Round 2
// baseline (443.423 us; speedup 1.0000x reference)
//
#include <hip/hip_runtime.h>
#include <hip/hip_bf16.h>

// Butterfly structure (BASE=3, FACTOR=0, n=27):
//   mask[s,t] != 0  iff  floor(s1/3)==floor(t1/3) && floor(s2/3)==floor(t2/3),
//   s = 27*s1 + s2.  81 groups g=(G1,G2); group members: 81*G1 + 27*i + 3*G2 + j.
//   attn packed: attn[g*81 + ls*9 + lt], g = 9*G1+G2, ls/lt = 3i+j.
// Dtypes: inputs fp32, output fp32.
//
// Round-1 lesson (measured): NEVER nontemporal-store the 12B-strided output
// pattern — partial-sector writebacks + RFO fetches blew traffic up 4.2x
// (WRITE 140->336 MB, FETCH 70->543 MB). Cached stores let L2 merge the
// wave's 3-dword-per-lane pattern into full lines (WRITE == exactly 140 MB).

__device__ __forceinline__ float gelu_f(float v) {
    // tanh-form gelu; |err| < ~7e-4, threshold 1.44e-2 (round-3 absmax 3.9e-3).
    float u2 = v * v;
    float z = -1.5957691216f * v * fmaf(0.044715f, u2, 1.0f);
    float e = __expf(z);
    return v * __builtin_amdgcn_rcpf(1.0f + e);
}

// ---------------- Kernel 0: zero attn scratch (ws is poisoned 0xAA) --------
__global__ void attn_zero_kernel(float* __restrict__ attn) {
    int i = blockIdx.x * 256 + threadIdx.x;
    if (i < 81 * 81) attn[i] = 0.0f;
}

// ---------------- Kernel 1: block-sparse attn = (w1^T . w2^T) .* mask ------
// Unchanged (measured: a few us, not on the critical path).
#define CH 108   // 27 chunks * 108 = 2916

__global__ __launch_bounds__(256) void bfly_attn_kernel(
        const float* __restrict__ w1,   // [2916, 729]
        const float* __restrict__ w2,   // [729, 2916]
        float* __restrict__ attn)       // [81*81], pre-zeroed
{
    const int G1    = blockIdx.x % 9;
    const int d0    = (blockIdx.x / 9) * CH;
    const int tid   = threadIdx.x;

    __shared__ float ws1[CH * 81];      // [dl][c]   34992 B
    __shared__ float ws2[81 * CH];      // [tl][dl]  34992 B

    for (int i = tid; i < CH * 81; i += 256) {
        int dl = i / 81, c = i % 81;
        ws1[i] = w1[(d0 + dl) * 729 + 81 * G1 + c];
    }
    for (int i = tid; i < 81 * CH; i += 256) {
        int tl = i / CH, dl = i % CH;
        ws2[i] = w2[(81 * G1 + tl) * 2916 + d0 + dl];
    }
    __syncthreads();

    if (tid < 243) {
        const int G2  = tid / 27;
        const int ls  = (tid % 27) / 3;
        const int lt0 = (tid % 3) * 3;
        const int s_l = 27 * (ls / 3) + 3 * G2 + (ls % 3);
        int t_l[3];
        #pragma unroll
        for (int j = 0; j < 3; ++j) {
            int lt = lt0 + j;
            t_l[j] = 27 * (lt / 3) + 3 * G2 + (lt % 3);
        }

        float a0 = 0.f, a1 = 0.f, a2 = 0.f;
        for (int dl = 0; dl < CH; ++dl) {
            float av = ws1[dl * 81 + s_l];
            a0 = fmaf(av, ws2[t_l[0] * CH + dl], a0);
            a1 = fmaf(av, ws2[t_l[1] * CH + dl], a1);
            a2 = fmaf(av, ws2[t_l[2] * CH + dl], a2);
        }

        const int g = 9 * G1 + G2;
        float* dst = &attn[g * 81 + ls * 9 + lt0];
        atomicAdd(dst + 0, a0);
        atomicAdd(dst + 1, a1);
        atomicAdd(dst + 2, a2);
    }
}

// ---------------- Kernel 2: out = gelu(x @ attn_blocksparse + b2) ----------
// Persistent double-buffered streaming structure:
//   - 1536 blocks (6/CU), each owns 8 tiles of ROWS=4 consecutive rows.
//   - LDS 2 x 11664 B = 23328 B -> 6 blocks/CU, 24 waves/CU.
//   - Staging via global_load_lds width=16 (no VGPR round trip, no ds_write).
//   - RAW s_barrier; the single vmcnt(0) sits BEFORE the next tile's loads
//     are issued, so prefetch for tile t+1 is in flight during the whole
//     compute of tile t.
//   - Stores deferred one tile (12 regs) so the vmcnt(0) only waits on
//     long-since-issued store-acks, never fresh ones.
#define ROWS 4
#define TPB  8          // tiles per block; 1536*8*4 = 49152 rows
#define NBLK 1536

struct f3 { float x, y, z; };   // 12 B, 4 B aligned -> global_store_dwordx3

__global__ __launch_bounds__(256, 6) void bfly_mlp_kernel(
        const float* __restrict__ xg,    // [49152, 729] fp32
        const float* __restrict__ attn,  // [81*81] fp32 (ws)
        const float* __restrict__ b2g,   // [729] fp32
        float* __restrict__ outg)        // [49152, 729] fp32
{
    __shared__ float xs[2][ROWS * 729];  // 2 x 11664 B

    const int tid = threadIdx.x;
    const bool active = (tid < 243);

    // Per-thread weights (hoisted once per block).
    float a[9][3], bias[3];
    int tb = 0, sb = 0;
    if (active) {
        const int t1 = tid / 9;           // 0..26
        const int G2 = tid % 9;           // 0..8
        const int G1 = t1 / 3;
        const int li = t1 % 3;
        tb = 3 * tid;                     // contiguous output triplet
        sb = 81 * G1 + 3 * G2;
        const int g  = 9 * G1 + G2;
        #pragma unroll
        for (int ls = 0; ls < 9; ++ls)
            #pragma unroll
            for (int j = 0; j < 3; ++j)
                a[ls][j] = attn[g * 81 + ls * 9 + 3 * li + j];
        #pragma unroll
        for (int j = 0; j < 3; ++j) bias[j] = b2g[tb + j];
    }

    const long long row0 = (long long)blockIdx.x * (ROWS * TPB);

    // Issue async global->LDS staging for tile t into buffer buf.
    // LDS dest is linear in lane id (i = tid + k*256 -> off = i*16 B):
    // wave-uniform base + lane*16, exactly what global_load_lds requires.
    auto stage = [&](int t, int buf) {
        const uint4* __restrict__ src =
            (const uint4*)(xg + (row0 + (long long)t * ROWS) * 729);
        #pragma unroll
        for (int k = 0; k < 3; ++k) {
            const int i = tid + k * 256;
            if (i < 729) {   // 729 uint4 = 4 rows * 2916 B
                __builtin_amdgcn_global_load_lds(
                    (const __attribute__((address_space(1))) void*)(src + i),
                    (__attribute__((address_space(3))) void*)(&xs[buf][i * 4]),
                    16, 0, 0);
            }
        }
    };

    int cur = 0;
    stage(0, 0);                 // prologue prefetch (one-time exposed latency)

    float res[ROWS][3];          // deferred (already-gelu'd) results

    for (int t = 0; t < TPB; ++t) {
        // Wait for tile t's loads (in flight during compute of t-1) and make
        // every wave's DMA writes visible block-wide.
        asm volatile("s_waitcnt vmcnt(0)" ::: "memory");
        __builtin_amdgcn_s_barrier();
        asm volatile("" ::: "memory");

        // Kick off tile t+1 immediately: in flight during ALL of this compute.
        // buf[cur^1]'s previous readers finished before the barrier above.
        if (t + 1 < TPB) stage(t + 1, cur ^ 1);

        if (active) {
            // Drain last tile's results. Plain cached stores: L2 merges the
            // wave's 12B-per-lane pattern into full lines (WRITE == 140 MB).
            if (t > 0) {
                const long long rb = (row0 + (long long)(t - 1) * ROWS) * 729 + tb;
                #pragma unroll
                for (int r = 0; r < ROWS; ++r) {
                    f3 v; v.x = res[r][0]; v.y = res[r][1]; v.z = res[r][2];
                    *reinterpret_cast<f3*>(&outg[rb + r * 729]) = v;
                }
            }

            const float* xb = &xs[cur][0];
            #pragma unroll
            for (int r = 0; r < ROWS; ++r) {
                const float* xr = xb + r * 729 + sb;
                float xv[9];
                #pragma unroll
                for (int i2 = 0; i2 < 3; ++i2)
                    #pragma unroll
                    for (int j2 = 0; j2 < 3; ++j2)
                        xv[3 * i2 + j2] = xr[27 * i2 + j2];

                float acc0 = bias[0], acc1 = bias[1], acc2 = bias[2];
                #pragma unroll
                for (int ls = 0; ls < 9; ++ls) {
                    acc0 = fmaf(xv[ls], a[ls][0], acc0);
                    acc1 = fmaf(xv[ls], a[ls][1], acc1);
                    acc2 = fmaf(xv[ls], a[ls][2], acc2);
                }
                res[r][0] = gelu_f(acc0);
                res[r][1] = gelu_f(acc1);
                res[r][2] = gelu_f(acc2);
            }
        }
        cur ^= 1;
    }

    // Epilogue: store the last tile's results.
    if (active) {
        const long long rb = (row0 + (long long)(TPB - 1) * ROWS) * 729 + tb;
        #pragma unroll
        for (int r = 0; r < ROWS; ++r) {
            f3 v; v.x = res[r][0]; v.y = res[r][1]; v.z = res[r][2];
            *reinterpret_cast<f3*>(&outg[rb + r * 729]) = v;
        }
    }
}

extern "C" void kernel_launch(void* const* d_in, const int* in_sizes, int n_in,
                              void* d_out, int out_size, void* d_ws, size_t ws_size,
                              hipStream_t stream) {
    const float* x  = (const float*)d_in[0];  // [64,768,729]
    const float* w1 = (const float*)d_in[1];  // [2916,729]
    const float* w2 = (const float*)d_in[2];  // [729,2916]
    const float* b2 = (const float*)d_in[3];  // [729]
    // d_in[4] = sparse_mask: static butterfly structure, never read.

    float* attn = (float*)d_ws;  // 26244 B scratch

    attn_zero_kernel<<<26, 256, 0, stream>>>(attn);
    bfly_attn_kernel<<<9 * 27, 256, 0, stream>>>(w1, w2, attn);

    bfly_mlp_kernel<<<NBLK, 256, 0, stream>>>(x, attn, b2, (float*)d_out);
}

// Round 4
// 280.893 us; speedup vs baseline: 1.5786x; 1.5786x over previous
//
#include <hip/hip_runtime.h>
#include <hip/hip_bf16.h>

// Butterfly structure (BASE=3, FACTOR=0, n=27):
//   mask[s,t] != 0  iff  floor(s1/3)==floor(t1/3) && floor(s2/3)==floor(t2/3),
//   s = 27*s1 + s2.  81 groups g=(G1,G2); group members: 81*G1 + 27*i + 3*G2 + j.
//   attn packed: attn[g*81 + ls*9 + lt], g = 9*G1+G2, ls/lt = 3i+j.
// Dtypes: inputs fp32, output fp32.
//
// Round-1/2 lesson (measured): the persistent global_load_lds + lockstep-
// barrier structure blew HBM traffic up 4.2x (WRITE 143->330 MB, FETCH
// 70->547 MB) regardless of store flavor (NT vs cached, dwordx3 vs 3xdword
// — identical counters). Machine-wide synchronized store bursts thrash the
// 4 MB/XCD L2 mid-merge: partial writebacks + RFO refetches. Keep stores
// phase-staggered and smooth.
//
// Round 3 was an infra failure (container died twice, no data) — this is a
// clean resubmit of the same kernel so the round-2 theory gets measured:
// x reuse is only 3x (threads sharing (G1,G2) differ in li) -> L1 serves it
// by line-hit; LDS staging + its barrier were pure overhead and the source
// of the burst-idle duty cycle. So: no LDS, no barriers, direct 12B triplet
// loads, full TLP.

__device__ __forceinline__ float gelu_f(float v) {
    // tanh-form gelu; |err| < ~7e-4, threshold 1.44e-2 (round-3 absmax 3.9e-3).
    float u2 = v * v;
    float z = -1.5957691216f * v * fmaf(0.044715f, u2, 1.0f);
    float e = __expf(z);
    return v * __builtin_amdgcn_rcpf(1.0f + e);
}

// ---------------- Kernel 0: zero attn scratch (ws is poisoned 0xAA) --------
__global__ void attn_zero_kernel(float* __restrict__ attn) {
    int i = blockIdx.x * 256 + threadIdx.x;
    if (i < 81 * 81) attn[i] = 0.0f;
}

// ---------------- Kernel 1: block-sparse attn = (w1^T . w2^T) .* mask ------
// Unchanged (measured: a few us, not on the critical path).
#define CH 108   // 27 chunks * 108 = 2916

__global__ __launch_bounds__(256) void bfly_attn_kernel(
        const float* __restrict__ w1,   // [2916, 729]
        const float* __restrict__ w2,   // [729, 2916]
        float* __restrict__ attn)       // [81*81], pre-zeroed
{
    const int G1    = blockIdx.x % 9;
    const int d0    = (blockIdx.x / 9) * CH;
    const int tid   = threadIdx.x;

    __shared__ float ws1[CH * 81];      // [dl][c]   34992 B
    __shared__ float ws2[81 * CH];      // [tl][dl]  34992 B

    for (int i = tid; i < CH * 81; i += 256) {
        int dl = i / 81, c = i % 81;
        ws1[i] = w1[(d0 + dl) * 729 + 81 * G1 + c];
    }
    for (int i = tid; i < 81 * CH; i += 256) {
        int tl = i / CH, dl = i % CH;
        ws2[i] = w2[(81 * G1 + tl) * 2916 + d0 + dl];
    }
    __syncthreads();

    if (tid < 243) {
        const int G2  = tid / 27;
        const int ls  = (tid % 27) / 3;
        const int lt0 = (tid % 3) * 3;
        const int s_l = 27 * (ls / 3) + 3 * G2 + (ls % 3);
        int t_l[3];
        #pragma unroll
        for (int j = 0; j < 3; ++j) {
            int lt = lt0 + j;
            t_l[j] = 27 * (lt / 3) + 3 * G2 + (lt % 3);
        }

        float a0 = 0.f, a1 = 0.f, a2 = 0.f;
        for (int dl = 0; dl < CH; ++dl) {
            float av = ws1[dl * 81 + s_l];
            a0 = fmaf(av, ws2[t_l[0] * CH + dl], a0);
            a1 = fmaf(av, ws2[t_l[1] * CH + dl], a1);
            a2 = fmaf(av, ws2[t_l[2] * CH + dl], a2);
        }

        const int g = 9 * G1 + G2;
        float* dst = &attn[g * 81 + ls * 9 + lt0];
        atomicAdd(dst + 0, a0);
        atomicAdd(dst + 1, a1);
        atomicAdd(dst + 2, a2);
    }
}

// ---------------- Kernel 2: out = gelu(x @ attn_blocksparse + b2) ----------
// No LDS, no barriers. Each thread owns output triplet tb=3*tid of ROWS
// consecutive rows: per row, 3x global_load_dwordx3 (12B, 3-lane-shared ->
// L1-merged), 27 FMA, 3 gelu, 1x global_store_dwordx3. Occupancy is
// VGPR-limited only; 6144 short-lived phase-staggered blocks keep the
// store stream smooth for L2 write-merge (round-0-proven clean traffic).
#define ROWS 8

struct f3 { float x, y, z; };   // 12 B, 4 B aligned -> dwordx3

__global__ __launch_bounds__(256) void bfly_mlp_kernel(
        const float* __restrict__ xg,    // [49152, 729] fp32
        const float* __restrict__ attn,  // [81*81] fp32 (ws)
        const float* __restrict__ b2g,   // [729] fp32
        float* __restrict__ outg)        // [49152, 729] fp32
{
    const int tid = threadIdx.x;
    if (tid >= 243) return;              // no barriers -> early exit is safe

    const int t1 = tid / 9;              // 0..26
    const int G2 = tid % 9;              // 0..8
    const int G1 = t1 / 3;
    const int li = t1 % 3;
    const int tb = 3 * tid;              // contiguous output triplet
    const int sb = 81 * G1 + 3 * G2;     // x column base (3 triplets @ stride 27)
    const int g  = 9 * G1 + G2;

    // Per-thread weights: 27 attn + 3 bias (L2-cached, amortized over ROWS).
    float a[9][3], bias[3];
    #pragma unroll
    for (int ls = 0; ls < 9; ++ls) {
        f3 v = *reinterpret_cast<const f3*>(&attn[g * 81 + ls * 9 + 3 * li]);
        a[ls][0] = v.x; a[ls][1] = v.y; a[ls][2] = v.z;
    }
    {
        f3 v = *reinterpret_cast<const f3*>(&b2g[tb]);
        bias[0] = v.x; bias[1] = v.y; bias[2] = v.z;
    }

    const long long rowbase = (long long)blockIdx.x * ROWS;
    const float* __restrict__ xbase = xg + rowbase * 729 + sb;

    #pragma unroll 2
    for (int r = 0; r < ROWS; ++r) {
        const float* xr = xbase + (long long)r * 729;
        f3 v0 = *reinterpret_cast<const f3*>(xr);
        f3 v1 = *reinterpret_cast<const f3*>(xr + 27);
        f3 v2 = *reinterpret_cast<const f3*>(xr + 54);
        float xv[9] = { v0.x, v0.y, v0.z, v1.x, v1.y, v1.z, v2.x, v2.y, v2.z };

        float acc0 = bias[0], acc1 = bias[1], acc2 = bias[2];
        #pragma unroll
        for (int ls = 0; ls < 9; ++ls) {
            acc0 = fmaf(xv[ls], a[ls][0], acc0);
            acc1 = fmaf(xv[ls], a[ls][1], acc1);
            acc2 = fmaf(xv[ls], a[ls][2], acc2);
        }

        f3 o; o.x = gelu_f(acc0); o.y = gelu_f(acc1); o.z = gelu_f(acc2);
        *reinterpret_cast<f3*>(&outg[(rowbase + r) * 729 + tb]) = o;
    }
}

extern "C" void kernel_launch(void* const* d_in, const int* in_sizes, int n_in,
                              void* d_out, int out_size, void* d_ws, size_t ws_size,
                              hipStream_t stream) {
    const float* x  = (const float*)d_in[0];  // [64,768,729]
    const float* w1 = (const float*)d_in[1];  // [2916,729]
    const float* w2 = (const float*)d_in[2];  // [729,2916]
    const float* b2 = (const float*)d_in[3];  // [729]
    // d_in[4] = sparse_mask: static butterfly structure, never read.

    float* attn = (float*)d_ws;  // 26244 B scratch

    attn_zero_kernel<<<26, 256, 0, stream>>>(attn);
    bfly_attn_kernel<<<9 * 27, 256, 0, stream>>>(w1, w2, attn);

    const int n_rows = 64 * 768;             // 49152
    bfly_mlp_kernel<<<n_rows / ROWS, 256, 0, stream>>>(
        x, attn, b2, (float*)d_out);
}

// Round 5
// 280.720 us; speedup vs baseline: 1.5796x; 1.0006x over previous
//
#include <hip/hip_runtime.h>
#include <hip/hip_bf16.h>

// Butterfly structure (BASE=3, FACTOR=0, n=27):
//   mask[s,t] != 0  iff  floor(s1/3)==floor(t1/3) && floor(s2/3)==floor(t2/3),
//   s = 27*s1 + s2.  81 groups g=(G1,G2); group members: 81*G1 + 27*i + 3*G2 + j.
//   attn packed: attn[g*81 + ls*9 + lt], g = 9*G1+G2, ls/lt = 3i+j.
// Dtypes: inputs fp32, output fp32.
//
// Measured history:
//   r0 (LDS-staged, ROWS=8):        mlp 88-92 us, traffic clean (FETCH 70 MB,
//                                   WRITE 140 MB), VALUBusy 21%, 2.4 TB/s eff.
//   r1/r2 (persistent global_load_lds + lockstep barriers): 253 us — machine-
//                                   wide store bursts thrash L2 mid-merge ->
//                                   4.2x traffic (WRITE 330, FETCH 547 MB).
//   r4 (direct dwordx3, unroll 2):  ~90 us (from total-const; masked in top-5
//                                   by 86 us harness poison-fills). Tie w/ r0.
//   Machine proof point: fillBufferAligned sustains 6.64 TB/s in the same run.
// Diagnosis: not traffic-, VALU-, or conflict-bound; ~2.4 TB/s effective at
// <40% of both pipes => latency-bound. unroll-2 keeps only ~1.5 KB/wave of
// loads in flight; poison-fills flush x from L3 every iteration, so loads see
// ~600-900 cy. This round: hoist ALL 8 rows' loads (24 dwordx3, ~18 KB/wave
// in flight, sched_barrier-pinned), then compute/store per row.

__device__ __forceinline__ float gelu_f(float v) {
    // tanh-form gelu; |err| < ~7e-4, threshold 1.44e-2 (measured absmax 3.9e-3).
    float u2 = v * v;
    float z = -1.5957691216f * v * fmaf(0.044715f, u2, 1.0f);
    float e = __expf(z);
    return v * __builtin_amdgcn_rcpf(1.0f + e);
}

// ---------------- Kernel 0: zero attn scratch (ws is poisoned 0xAA) --------
__global__ void attn_zero_kernel(float* __restrict__ attn) {
    int i = blockIdx.x * 256 + threadIdx.x;
    if (i < 81 * 81) attn[i] = 0.0f;
}

// ---------------- Kernel 1: block-sparse attn = (w1^T . w2^T) .* mask ------
// Unchanged (measured: a few us, not on the critical path).
#define CH 108   // 27 chunks * 108 = 2916

__global__ __launch_bounds__(256) void bfly_attn_kernel(
        const float* __restrict__ w1,   // [2916, 729]
        const float* __restrict__ w2,   // [729, 2916]
        float* __restrict__ attn)       // [81*81], pre-zeroed
{
    const int G1    = blockIdx.x % 9;
    const int d0    = (blockIdx.x / 9) * CH;
    const int tid   = threadIdx.x;

    __shared__ float ws1[CH * 81];      // [dl][c]   34992 B
    __shared__ float ws2[81 * CH];      // [tl][dl]  34992 B

    for (int i = tid; i < CH * 81; i += 256) {
        int dl = i / 81, c = i % 81;
        ws1[i] = w1[(d0 + dl) * 729 + 81 * G1 + c];
    }
    for (int i = tid; i < 81 * CH; i += 256) {
        int tl = i / CH, dl = i % CH;
        ws2[i] = w2[(81 * G1 + tl) * 2916 + d0 + dl];
    }
    __syncthreads();

    if (tid < 243) {
        const int G2  = tid / 27;
        const int ls  = (tid % 27) / 3;
        const int lt0 = (tid % 3) * 3;
        const int s_l = 27 * (ls / 3) + 3 * G2 + (ls % 3);
        int t_l[3];
        #pragma unroll
        for (int j = 0; j < 3; ++j) {
            int lt = lt0 + j;
            t_l[j] = 27 * (lt / 3) + 3 * G2 + (lt % 3);
        }

        float a0 = 0.f, a1 = 0.f, a2 = 0.f;
        for (int dl = 0; dl < CH; ++dl) {
            float av = ws1[dl * 81 + s_l];
            a0 = fmaf(av, ws2[t_l[0] * CH + dl], a0);
            a1 = fmaf(av, ws2[t_l[1] * CH + dl], a1);
            a2 = fmaf(av, ws2[t_l[2] * CH + dl], a2);
        }

        const int g = 9 * G1 + G2;
        float* dst = &attn[g * 81 + ls * 9 + lt0];
        atomicAdd(dst + 0, a0);
        atomicAdd(dst + 1, a1);
        atomicAdd(dst + 2, a2);
    }
}

// ---------------- Kernel 2: out = gelu(x @ attn_blocksparse + b2) ----------
// No LDS, no barriers. Each thread owns output triplet tb=3*tid of ROWS
// consecutive rows. Phase 1: issue ALL ROWS*3 dwordx3 loads (deep MLP,
// ~18 KB/wave in flight). Phase 2: per row, 27 FMA + 3 gelu + dwordx3 store,
// with compiler vmcnt(N) waits overlapping compute of row r against loads
// of rows r+1.. still in flight. All xv indices compile-time (full unroll)
// so the array lives in registers (rule: runtime-indexed arrays -> scratch).
#define ROWS 8

struct f3 { float x, y, z; };   // 12 B, 4 B aligned -> dwordx3

__global__ __launch_bounds__(256) void bfly_mlp_kernel(
        const float* __restrict__ xg,    // [49152, 729] fp32
        const float* __restrict__ attn,  // [81*81] fp32 (ws)
        const float* __restrict__ b2g,   // [729] fp32
        float* __restrict__ outg)        // [49152, 729] fp32
{
    const int tid = threadIdx.x;
    if (tid >= 243) return;              // no barriers -> early exit is safe

    const int t1 = tid / 9;              // 0..26
    const int G2 = tid % 9;              // 0..8
    const int G1 = t1 / 3;
    const int li = t1 % 3;
    const int tb = 3 * tid;              // contiguous output triplet
    const int sb = 81 * G1 + 3 * G2;     // x column base (3 triplets @ stride 27)
    const int g  = 9 * G1 + G2;

    const long long rowbase = (long long)blockIdx.x * ROWS;
    const float* __restrict__ xbase = xg + rowbase * 729 + sb;

    // ---- Phase 1: issue every row's loads back-to-back (24 dwordx3) ----
    float xv[ROWS][9];
    #pragma unroll
    for (int r = 0; r < ROWS; ++r) {
        const float* xr = xbase + r * 729;
        f3 v0 = *reinterpret_cast<const f3*>(xr);
        f3 v1 = *reinterpret_cast<const f3*>(xr + 27);
        f3 v2 = *reinterpret_cast<const f3*>(xr + 54);
        xv[r][0] = v0.x; xv[r][1] = v0.y; xv[r][2] = v0.z;
        xv[r][3] = v1.x; xv[r][4] = v1.y; xv[r][5] = v1.z;
        xv[r][6] = v2.x; xv[r][7] = v2.y; xv[r][8] = v2.z;
    }
    // Pin the schedule: loads stay above, compute below (prevents the
    // scheduler from sinking loads back into phase 2 and shrinking MLP).
    __builtin_amdgcn_sched_barrier(0);

    // Weights AFTER the x burst (their latency hides under it; L2-hot after
    // the first few blocks anyway).
    float a[9][3], bias[3];
    #pragma unroll
    for (int ls = 0; ls < 9; ++ls) {
        f3 v = *reinterpret_cast<const f3*>(&attn[g * 81 + ls * 9 + 3 * li]);
        a[ls][0] = v.x; a[ls][1] = v.y; a[ls][2] = v.z;
    }
    {
        f3 v = *reinterpret_cast<const f3*>(&b2g[tb]);
        bias[0] = v.x; bias[1] = v.y; bias[2] = v.z;
    }

    // ---- Phase 2: compute + store per row ----
    #pragma unroll
    for (int r = 0; r < ROWS; ++r) {
        float acc0 = bias[0], acc1 = bias[1], acc2 = bias[2];
        #pragma unroll
        for (int ls = 0; ls < 9; ++ls) {
            acc0 = fmaf(xv[r][ls], a[ls][0], acc0);
            acc1 = fmaf(xv[r][ls], a[ls][1], acc1);
            acc2 = fmaf(xv[r][ls], a[ls][2], acc2);
        }
        f3 o; o.x = gelu_f(acc0); o.y = gelu_f(acc1); o.z = gelu_f(acc2);
        *reinterpret_cast<f3*>(&outg[(rowbase + r) * 729 + tb]) = o;
    }
}

extern "C" void kernel_launch(void* const* d_in, const int* in_sizes, int n_in,
                              void* d_out, int out_size, void* d_ws, size_t ws_size,
                              hipStream_t stream) {
    const float* x  = (const float*)d_in[0];  // [64,768,729]
    const float* w1 = (const float*)d_in[1];  // [2916,729]
    const float* w2 = (const float*)d_in[2];  // [729,2916]
    const float* b2 = (const float*)d_in[3];  // [729]
    // d_in[4] = sparse_mask: static butterfly structure, never read.

    float* attn = (float*)d_ws;  // 26244 B scratch

    attn_zero_kernel<<<26, 256, 0, stream>>>(attn);
    bfly_attn_kernel<<<9 * 27, 256, 0, stream>>>(w1, w2, attn);

    const int n_rows = 64 * 768;             // 49152
    bfly_mlp_kernel<<<n_rows / ROWS, 256, 0, stream>>>(
        x, attn, b2, (float*)d_out);
}

// Round 6
// 279.466 us; speedup vs baseline: 1.5867x; 1.0045x over previous
//
#include <hip/hip_runtime.h>
#include <hip/hip_bf16.h>

// Butterfly structure (BASE=3, FACTOR=0, n=27):
//   mask[s,t] != 0  iff  floor(s1/3)==floor(t1/3) && floor(s2/3)==floor(t2/3),
//   s = 27*s1 + s2.  81 groups g=(G1,G2); group members: 81*G1 + 27*i + 3*G2 + j.
//   attn packed: attn[g*81 + ls*9 + lt], g = 9*G1+G2, ls/lt = 3i+j.
// Dtypes: inputs fp32, output fp32.
//
// Measured history:
//   r0 (LDS-staged loads, 12B scatter stores): 88-92 us, clean traffic.
//   r1/r2 (persistent + lockstep barriers):    253 us, 4.2x traffic (L2
//        thrash from machine-wide store bursts). Avoid persistent lockstep.
//   r4 (direct dwordx3, shallow):              ~90 us.
//   r5 (direct dwordx3, 8-row deep burst):     86.8 us. Occupancy HALVED vs
//        r0 (55->26%) with zero perf change; VALUBusy 20%; traffic clean;
//        fill hits 6.7 TB/s in-run. => Not latency-, occupancy-, VALU-,
//        conflict-, or HBM-byte-bound.
// Surviving theory: TA/TCP vector-memory pipe saturated by per-lane small-
// granularity VMEM instructions (12 B lane stride => dozens of line touches
// per instruction; ~50 cy/instr available and likely consumed).
// This round: EVERY global access is a contiguous full-wave dwordx4
// (16 B/lane). 12B-granularity work moves to the idle LDS pipe.
//   stage x (uint4, ~6 instr/wave) -> barrier -> compute from LDS into regs
//   -> barrier -> write results into same LDS -> barrier -> store (uint4,
//   ~6 instr/wave). VMEM instr/wave: 42 -> ~22, all minimal-line-touch.

__device__ __forceinline__ float gelu_f(float v) {
    // tanh-form gelu; |err| < ~7e-4, threshold 1.44e-2 (measured absmax 3.9e-3).
    float u2 = v * v;
    float z = -1.5957691216f * v * fmaf(0.044715f, u2, 1.0f);
    float e = __expf(z);
    return v * __builtin_amdgcn_rcpf(1.0f + e);
}

// ---------------- Kernel 0: zero attn scratch (ws is poisoned 0xAA) --------
__global__ void attn_zero_kernel(float* __restrict__ attn) {
    int i = blockIdx.x * 256 + threadIdx.x;
    if (i < 81 * 81) attn[i] = 0.0f;
}

// ---------------- Kernel 1: block-sparse attn = (w1^T . w2^T) .* mask ------
// Unchanged (measured: a few us, not on the critical path).
#define CH 108   // 27 chunks * 108 = 2916

__global__ __launch_bounds__(256) void bfly_attn_kernel(
        const float* __restrict__ w1,   // [2916, 729]
        const float* __restrict__ w2,   // [729, 2916]
        float* __restrict__ attn)       // [81*81], pre-zeroed
{
    const int G1    = blockIdx.x % 9;
    const int d0    = (blockIdx.x / 9) * CH;
    const int tid   = threadIdx.x;

    __shared__ float ws1[CH * 81];      // [dl][c]   34992 B
    __shared__ float ws2[81 * CH];      // [tl][dl]  34992 B

    for (int i = tid; i < CH * 81; i += 256) {
        int dl = i / 81, c = i % 81;
        ws1[i] = w1[(d0 + dl) * 729 + 81 * G1 + c];
    }
    for (int i = tid; i < 81 * CH; i += 256) {
        int tl = i / CH, dl = i % CH;
        ws2[i] = w2[(81 * G1 + tl) * 2916 + d0 + dl];
    }
    __syncthreads();

    if (tid < 243) {
        const int G2  = tid / 27;
        const int ls  = (tid % 27) / 3;
        const int lt0 = (tid % 3) * 3;
        const int s_l = 27 * (ls / 3) + 3 * G2 + (ls % 3);
        int t_l[3];
        #pragma unroll
        for (int j = 0; j < 3; ++j) {
            int lt = lt0 + j;
            t_l[j] = 27 * (lt / 3) + 3 * G2 + (lt % 3);
        }

        float a0 = 0.f, a1 = 0.f, a2 = 0.f;
        for (int dl = 0; dl < CH; ++dl) {
            float av = ws1[dl * 81 + s_l];
            a0 = fmaf(av, ws2[t_l[0] * CH + dl], a0);
            a1 = fmaf(av, ws2[t_l[1] * CH + dl], a1);
            a2 = fmaf(av, ws2[t_l[2] * CH + dl], a2);
        }

        const int g = 9 * G1 + G2;
        float* dst = &attn[g * 81 + ls * 9 + lt0];
        atomicAdd(dst + 0, a0);
        atomicAdd(dst + 1, a1);
        atomicAdd(dst + 2, a2);
    }
}

// ---------------- Kernel 2: out = gelu(x @ attn_blocksparse + b2) ----------
// All-coalesced VMEM version. TILE=8 rows/block, one 23328 B LDS buffer
// (6 blocks/CU), 3 barriers, short-lived blocks (no persistent lockstep).
#define TILE 8
#define NV4  (TILE * 729 / 4)   // 1458 uint4 per tile (8 rows = 729 uint4 pairs)

struct f3 { float x, y, z; };

__global__ __launch_bounds__(256) void bfly_mlp_kernel(
        const float* __restrict__ xg,    // [49152, 729] fp32
        const float* __restrict__ attn,  // [81*81] fp32 (ws)
        const float* __restrict__ b2g,   // [729] fp32
        float* __restrict__ outg)        // [49152, 729] fp32
{
    __shared__ float xs[TILE * 729];     // 23328 B, reused for out

    const int tid = threadIdx.x;
    const bool active = (tid < 243);

    // Per-thread weights first: their (deduped, L2-hot) loads overlap the
    // x staging burst below.
    float a[9][3], bias[3];
    int tb = 0, sb = 0;
    if (active) {
        const int t1 = tid / 9;           // 0..26
        const int G2 = tid % 9;           // 0..8
        const int G1 = t1 / 3;
        const int li = t1 % 3;
        tb = 3 * tid;                     // contiguous output triplet
        sb = 81 * G1 + 3 * G2;            // x column base (3 triplets @ 27)
        const int g  = 9 * G1 + G2;
        #pragma unroll
        for (int ls = 0; ls < 9; ++ls) {
            f3 v = *reinterpret_cast<const f3*>(&attn[g * 81 + ls * 9 + 3 * li]);
            a[ls][0] = v.x; a[ls][1] = v.y; a[ls][2] = v.z;
        }
        f3 v = *reinterpret_cast<const f3*>(&b2g[tb]);
        bias[0] = v.x; bias[1] = v.y; bias[2] = v.z;
    }

    const long long rowbase = (long long)blockIdx.x * TILE;

    // ---- Stage: 1458 contiguous uint4 loads (fully coalesced, 16 B/lane).
    // Base byte offset rowbase*2916 is 16B-aligned (rowbase multiple of 8).
    {
        const uint4* __restrict__ src = (const uint4*)(xg + rowbase * 729);
        uint4* dst = (uint4*)xs;
        #pragma unroll
        for (int k = 0; k < 6; ++k) {
            int i = tid + k * 256;
            if (i < NV4) dst[i] = src[i];
        }
    }
    __syncthreads();

    // ---- Compute: 8 rows x 3 outputs into 24 registers (static indices).
    float res[TILE][3];
    if (active) {
        #pragma unroll
        for (int r = 0; r < TILE; ++r) {
            const float* xr = &xs[r * 729 + sb];
            float xv[9];
            #pragma unroll
            for (int i2 = 0; i2 < 3; ++i2)
                #pragma unroll
                for (int j2 = 0; j2 < 3; ++j2)
                    xv[3 * i2 + j2] = xr[27 * i2 + j2];

            float acc0 = bias[0], acc1 = bias[1], acc2 = bias[2];
            #pragma unroll
            for (int ls = 0; ls < 9; ++ls) {
                acc0 = fmaf(xv[ls], a[ls][0], acc0);
                acc1 = fmaf(xv[ls], a[ls][1], acc1);
                acc2 = fmaf(xv[ls], a[ls][2], acc2);
            }
            res[r][0] = gelu_f(acc0);
            res[r][1] = gelu_f(acc1);
            res[r][2] = gelu_f(acc2);
        }
    }
    __syncthreads();   // all reads of xs done before overwrite

    // ---- Writeback to LDS: 12 B/lane scatter goes to the LDS pipe (idle),
    // not the TA pipe. Stride-3-float => 2-way bank aliasing (free, m136).
    if (active) {
        #pragma unroll
        for (int r = 0; r < TILE; ++r) {
            float* o = &xs[r * 729 + tb];
            o[0] = res[r][0]; o[1] = res[r][1]; o[2] = res[r][2];
        }
    }
    __syncthreads();

    // ---- Store: 1458 contiguous uint4 stores (fully coalesced, 16 B/lane).
    {
        uint4* __restrict__ dst = (uint4*)(outg + rowbase * 729);
        const uint4* src = (const uint4*)xs;
        #pragma unroll
        for (int k = 0; k < 6; ++k) {
            int i = tid + k * 256;
            if (i < NV4) dst[i] = src[i];
        }
    }
}

extern "C" void kernel_launch(void* const* d_in, const int* in_sizes, int n_in,
                              void* d_out, int out_size, void* d_ws, size_t ws_size,
                              hipStream_t stream) {
    const float* x  = (const float*)d_in[0];  // [64,768,729]
    const float* w1 = (const float*)d_in[1];  // [2916,729]
    const float* w2 = (const float*)d_in[2];  // [729,2916]
    const float* b2 = (const float*)d_in[3];  // [729]
    // d_in[4] = sparse_mask: static butterfly structure, never read.

    float* attn = (float*)d_ws;  // 26244 B scratch

    attn_zero_kernel<<<26, 256, 0, stream>>>(attn);
    bfly_attn_kernel<<<9 * 27, 256, 0, stream>>>(w1, w2, attn);

    const int n_rows = 64 * 768;             // 49152
    bfly_mlp_kernel<<<n_rows / TILE, 256, 0, stream>>>(
        x, attn, b2, (float*)d_out);
}